// Round 9
// baseline (432.135 us; speedup 1.0000x reference)
//
#include <hip/hip_runtime.h>
#include <math.h>

#define NN   100000
#define EE   1600000
#define FIN  256
#define NCLS 16
#define NEG  0.2f

#define NEDGE (EE + NN)     // with self-loops
#define WBKT  256           // dsts per bucket
#define NBKT  ((NN + WBKT - 1) / WBKT)   // 391
#define CAP   5120          // per-bucket capacity (mean 4352)
#define ABLK  4096          // edges per binA block
#define NABLK ((NEDGE + ABLK - 1) / ABLK)  // 416

// ---- workspace layout (4-byte element offsets) ----
#define OFF_GCNT  0                          // [392] zeroed each call
#define OFF_BASE  392                        // [392]
#define OFF_ROW   784                        // [NN+1]
#define OFF_BKT   100788                     // [NBKT*CAP] packed (src<<8)|dlow
#define OFF_ADJ   (OFF_BKT + NBKT*CAP)       // [NEDGE]
#define OFF_H1B   (OFF_ADJ + NEDGE)          // [NN*64] bf16 (pre-attn values)
#define OFF_H1E   (OFF_H1B + NN*32)          // [NN*64] bf16 (post-ELU)
#define OFF_AL1S  (OFF_H1E + NN*32)          // [NN*8]
#define OFF_AL1D  (OFF_AL1S + NN*8)          // [NN*8]
#define OFF_H2B   (OFF_AL1D + NN*8)          // [NN*16] bf16
#define OFF_AL2S  (OFF_H2B + NN*8)           // [NN]
#define OFF_AL2D  (OFF_AL2S + NN)            // [NN]

typedef unsigned uv4 __attribute__((ext_vector_type(4)));

__device__ __forceinline__ float lrelu(float x) { return x >= 0.f ? x : NEG * x; }
__device__ __forceinline__ unsigned short f2bf(float x) {
    unsigned u = __float_as_uint(x);
    return (unsigned short)((u + 0x7FFF + ((u >> 16) & 1)) >> 16);   // RNE
}
__device__ __forceinline__ float bf2f(unsigned short b) {
    return __uint_as_float(((unsigned)b) << 16);
}
__device__ __forceinline__ float bflo(unsigned u) { return __uint_as_float(u << 16); }
__device__ __forceinline__ float bfhi(unsigned u) { return __uint_as_float(u & 0xFFFF0000u); }

// ---------- CSR build, phase A: bin edges by dst>>8 ----------
__global__ __launch_bounds__(256) void k_binA(
    const int* __restrict__ esrc, const int* __restrict__ edst,
    int* __restrict__ gcnt, unsigned* __restrict__ bkt)
{
    __shared__ int lcnt[NBKT];
    __shared__ int lbase[NBKT];
    const int t = threadIdx.x;
    const int e0 = blockIdx.x * ABLK;
    for (int i = t; i < NBKT; i += 256) lcnt[i] = 0;
    __syncthreads();

    unsigned wrd[16];
    unsigned short bb[16], ll[16];
    #pragma unroll
    for (int j = 0; j < 16; ++j) {
        int ei = e0 + j * 256 + t;
        bb[j] = 0xFFFFu;
        if (ei < NEDGE) {
            int s, d;
            if (ei < EE) { s = esrc[ei]; d = edst[ei]; } else { s = d = ei - EE; }
            int b = d >> 8;
            wrd[j] = ((unsigned)s << 8) | (unsigned)(d & 255);
            bb[j] = (unsigned short)b;
            ll[j] = (unsigned short)atomicAdd(&lcnt[b], 1);
        }
    }
    __syncthreads();
    for (int i = t; i < NBKT; i += 256)
        lbase[i] = lcnt[i] ? atomicAdd(&gcnt[i], lcnt[i]) : 0;
    __syncthreads();
    #pragma unroll
    for (int j = 0; j < 16; ++j) {
        if (bb[j] != 0xFFFFu) {
            int b = bb[j];
            __builtin_nontemporal_store(wrd[j], &bkt[(size_t)b * CAP + lbase[b] + ll[j]]);
        }
    }
}

// ---------- CSR build, phase B: scan bucket counts -> bases ----------
__global__ __launch_bounds__(512) void k_scanB(
    const int* __restrict__ gcnt, int* __restrict__ base, int* __restrict__ row)
{
    __shared__ int s[512];
    int t = threadIdx.x;
    int v = (t < NBKT) ? gcnt[t] : 0;
    s[t] = v;
    __syncthreads();
    for (int off = 1; off < 512; off <<= 1) {
        int u = (t >= off) ? s[t - off] : 0;
        __syncthreads();
        s[t] += u;
        __syncthreads();
    }
    if (t <= NBKT) base[t] = s[t] - v;   // exclusive; base[NBKT] = NEDGE
    if (t == 0) row[NN] = NEDGE;
}

// ---------- CSR build, phase C: per-bucket local sort -> row + adj ----------
__global__ __launch_bounds__(256) void k_binC(
    const int* __restrict__ gcnt, const int* __restrict__ base,
    const unsigned* __restrict__ bkt, int* __restrict__ row, int* __restrict__ adj)
{
    __shared__ unsigned wd[CAP];          // 20 KB stage
    __shared__ int hist[256], pref[256], cnt2[256];
    const int g = blockIdx.x, t = threadIdx.x;
    const int cn = gcnt[g], bs = base[g];
    hist[t] = 0; cnt2[t] = 0;
    __syncthreads();
    for (int i = t; i < cn; i += 256) {
        unsigned w = __builtin_nontemporal_load(&bkt[(size_t)g * CAP + i]);
        wd[i] = w;
        atomicAdd(&hist[w & 255], 1);
    }
    __syncthreads();
    int v = hist[t];
    pref[t] = v;
    __syncthreads();
    for (int off = 1; off < 256; off <<= 1) {
        int u = (t >= off) ? pref[t - off] : 0;
        __syncthreads();
        pref[t] += u;
        __syncthreads();
    }
    int ex = pref[t] - v;                 // exclusive local prefix
    int n = g * 256 + t;
    if (n < NN) row[n] = bs + ex;
    pref[t] = ex;
    __syncthreads();
    for (int i = t; i < cn; i += 256) {
        unsigned w = wd[i];
        int dl = w & 255;
        int p = atomicAdd(&cnt2[dl], 1);
        adj[bs + pref[dl] + p] = (int)(w >> 8);
    }
}

// ---------- layer 1 GEMM: 64x64 tile, 4x4 register tile; bf16 value output ----------
__global__ __launch_bounds__(256) void k_gemm1(
    const float* __restrict__ x, const float* __restrict__ W1,
    const float* __restrict__ a1s, const float* __restrict__ a1d,
    unsigned short* __restrict__ h1b, float* __restrict__ al1s, float* __restrict__ al1d)
{
    __shared__ float sxT[32][68];
    __shared__ float sW[32][64];
    const int t = threadIdx.x;
    const int n0 = blockIdx.x * 64;
    const int tr = t >> 4, tc = t & 15;

    float acc[4][4] = {};

    for (int kc = 0; kc < 256; kc += 32) {
        __syncthreads();
        #pragma unroll
        for (int it = 0; it < 2; ++it) {
            int i = t + it * 256;
            int r = i >> 3, fj = i & 7;
            int n = n0 + r;
            float4 v = (n < NN) ? *(const float4*)(x + (size_t)n * FIN + kc + fj * 4)
                                : make_float4(0.f, 0.f, 0.f, 0.f);
            sxT[fj * 4 + 0][r] = v.x;
            sxT[fj * 4 + 1][r] = v.y;
            sxT[fj * 4 + 2][r] = v.z;
            sxT[fj * 4 + 3][r] = v.w;
        }
        #pragma unroll
        for (int it = 0; it < 2; ++it) {
            int i = t + it * 256;
            int r = i >> 4, fj = i & 15;
            *(float4*)&sW[r][fj * 4] = *(const float4*)(W1 + (size_t)(kc + r) * 64 + fj * 4);
        }
        __syncthreads();
        #pragma unroll
        for (int k = 0; k < 32; ++k) {
            float4 a = *(const float4*)&sxT[k][tr * 4];
            float4 b = *(const float4*)&sW[k][tc * 4];
            acc[0][0] += a.x * b.x; acc[0][1] += a.x * b.y; acc[0][2] += a.x * b.z; acc[0][3] += a.x * b.w;
            acc[1][0] += a.y * b.x; acc[1][1] += a.y * b.y; acc[1][2] += a.y * b.z; acc[1][3] += a.y * b.w;
            acc[2][0] += a.z * b.x; acc[2][1] += a.z * b.y; acc[2][2] += a.z * b.z; acc[2][3] += a.z * b.w;
            acc[3][0] += a.w * b.x; acc[3][1] += a.w * b.y; acc[3][2] += a.w * b.z; acc[3][3] += a.w * b.w;
        }
    }

    #pragma unroll
    for (int j = 0; j < 4; ++j) {
        int n = n0 + tr * 4 + j;
        if (n < NN) {
            ushort4 v = make_ushort4(f2bf(acc[j][0]), f2bf(acc[j][1]), f2bf(acc[j][2]), f2bf(acc[j][3]));
            *(ushort4*)(h1b + (size_t)n * 64 + tc * 4) = v;
        }
    }

    float sa[4], da[4];
    #pragma unroll
    for (int u = 0; u < 4; ++u) { sa[u] = a1s[tc * 4 + u]; da[u] = a1d[tc * 4 + u]; }
    #pragma unroll
    for (int j = 0; j < 4; ++j) {
        float vs = acc[j][0] * sa[0] + acc[j][1] * sa[1] + acc[j][2] * sa[2] + acc[j][3] * sa[3];
        float vd = acc[j][0] * da[0] + acc[j][1] * da[1] + acc[j][2] * da[2] + acc[j][3] * da[3];
        vs += __shfl_xor(vs, 1, 64);
        vd += __shfl_xor(vd, 1, 64);
        int n = n0 + tr * 4 + j;
        if (!(tc & 1) && n < NN) {
            al1s[n * 8 + (tc >> 1)] = vs;
            al1d[n * 8 + (tc >> 1)] = vd;
        }
    }
}

// ---------- layer 1 aggregation: 8 edges x 8 head-lanes, uint4 payload ----------
__global__ __launch_bounds__(256) void k_agg1(
    const int* __restrict__ row, const int* __restrict__ adj,
    const float* __restrict__ al1s, const float* __restrict__ al1d,
    const uv4* __restrict__ h1bq, const float* __restrict__ b1,
    uv4* __restrict__ h1eq)
{
    const int wv = threadIdx.x >> 6, lane = threadIdx.x & 63;
    const int n = blockIdx.x * 4 + wv;
    const int eg = lane >> 3;          // edge group 0..7
    const int h  = lane & 7;           // head == channel octet
    const float ald = al1d[n * 8 + h];
    const int r0 = row[n], r1 = row[n + 1];

    float dsum = 0.f;
    float a0 = 0.f, a1 = 0.f, a2 = 0.f, a3 = 0.f;
    float a4 = 0.f, a5 = 0.f, a6 = 0.f, a7 = 0.f;
    #pragma unroll 2
    for (int i = r0 + eg; i < r1; i += 8) {
        int s = __builtin_nontemporal_load(&adj[i]);
        float w = __expf(lrelu(al1s[s * 8 + h] + ald));
        uv4 u = __builtin_nontemporal_load(&h1bq[s * 8 + h]);
        dsum += w;
        a0 += w * bflo(u.x); a1 += w * bfhi(u.x);
        a2 += w * bflo(u.y); a3 += w * bfhi(u.y);
        a4 += w * bflo(u.z); a5 += w * bfhi(u.z);
        a6 += w * bflo(u.w); a7 += w * bfhi(u.w);
    }
    // reduce over the 8 edge groups
    #pragma unroll
    for (int off = 8; off < 64; off <<= 1) {
        dsum += __shfl_xor(dsum, off, 64);
        a0 += __shfl_xor(a0, off, 64); a1 += __shfl_xor(a1, off, 64);
        a2 += __shfl_xor(a2, off, 64); a3 += __shfl_xor(a3, off, 64);
        a4 += __shfl_xor(a4, off, 64); a5 += __shfl_xor(a5, off, 64);
        a6 += __shfl_xor(a6, off, 64); a7 += __shfl_xor(a7, off, 64);
    }
    if (eg != 0) return;

    float inv = 1.f / dsum;
    float4 bL = *(const float4*)(b1 + h * 8);
    float4 bH = *(const float4*)(b1 + h * 8 + 4);
    float v0 = a0 * inv + bL.x, v1 = a1 * inv + bL.y;
    float v2 = a2 * inv + bL.z, v3 = a3 * inv + bL.w;
    float v4 = a4 * inv + bH.x, v5 = a5 * inv + bH.y;
    float v6 = a6 * inv + bH.z, v7 = a7 * inv + bH.w;
    v0 = v0 > 0.f ? v0 : __expf(v0) - 1.f;
    v1 = v1 > 0.f ? v1 : __expf(v1) - 1.f;
    v2 = v2 > 0.f ? v2 : __expf(v2) - 1.f;
    v3 = v3 > 0.f ? v3 : __expf(v3) - 1.f;
    v4 = v4 > 0.f ? v4 : __expf(v4) - 1.f;
    v5 = v5 > 0.f ? v5 : __expf(v5) - 1.f;
    v6 = v6 > 0.f ? v6 : __expf(v6) - 1.f;
    v7 = v7 > 0.f ? v7 : __expf(v7) - 1.f;
    uv4 o;
    o.x = (unsigned)f2bf(v0) | ((unsigned)f2bf(v1) << 16);
    o.y = (unsigned)f2bf(v2) | ((unsigned)f2bf(v3) << 16);
    o.z = (unsigned)f2bf(v4) | ((unsigned)f2bf(v5) << 16);
    o.w = (unsigned)f2bf(v6) | ((unsigned)f2bf(v7) << 16);
    h1eq[n * 8 + h] = o;
}

// ---------- layer 2 GEMM: h2b = bf16(h1e @ W2), al2s/al2d logits ----------
__global__ __launch_bounds__(256) void k_gemm2(
    const uv4* __restrict__ h1eq, const float* __restrict__ W2,
    const float* __restrict__ a2s, const float* __restrict__ a2d,
    unsigned short* __restrict__ h2b, float* __restrict__ al2s, float* __restrict__ al2d)
{
    __shared__ float sW[64 * 16];
    const int t = threadIdx.x;
    for (int i = t; i < 64 * 16; i += 256) sW[i] = W2[i];
    __syncthreads();
    const int n = blockIdx.x * 16 + (t >> 4);
    const int k = t & 15;
    const uv4* hr = h1eq + (size_t)n * 8;
    float acc = 0.f;
    #pragma unroll
    for (int q = 0; q < 8; ++q) {
        uv4 u = hr[q];
        acc += bflo(u.x) * sW[(q * 8 + 0) * 16 + k] + bfhi(u.x) * sW[(q * 8 + 1) * 16 + k]
             + bflo(u.y) * sW[(q * 8 + 2) * 16 + k] + bfhi(u.y) * sW[(q * 8 + 3) * 16 + k]
             + bflo(u.z) * sW[(q * 8 + 4) * 16 + k] + bfhi(u.z) * sW[(q * 8 + 5) * 16 + k]
             + bflo(u.w) * sW[(q * 8 + 6) * 16 + k] + bfhi(u.w) * sW[(q * 8 + 7) * 16 + k];
    }
    h2b[(size_t)n * 16 + k] = f2bf(acc);
    float vs = acc * a2s[k], vd = acc * a2d[k];
    #pragma unroll
    for (int off = 1; off < 16; off <<= 1) {
        vs += __shfl_xor(vs, off, 64);
        vd += __shfl_xor(vd, off, 64);
    }
    if (k == 0) { al2s[n] = vs; al2d[n] = vd; }
}

// ---------- layer 2 aggregation: 8 edges x 8 chpair-lanes, packed ----------
__global__ __launch_bounds__(256) void k_agg2(
    const int* __restrict__ row, const int* __restrict__ adj,
    const float* __restrict__ al2s, const float* __restrict__ al2d,
    const unsigned* __restrict__ h2b2, const float* __restrict__ b2,
    float* __restrict__ out)
{
    const int wv = threadIdx.x >> 6, lane = threadIdx.x & 63;
    const int n = blockIdx.x * 4 + wv;
    const float ald = al2d[n];
    const int r0 = row[n], r1 = row[n + 1];

    const int j = lane >> 3;    // edge slot 0..7
    const int c = lane & 7;     // channel pair -> channels 2c, 2c+1
    float dsum = 0.f, ax = 0.f, ay = 0.f;
    #pragma unroll 2
    for (int i = r0 + j; i < r1; i += 8) {
        int s = __builtin_nontemporal_load(&adj[i]);
        float w = __expf(lrelu(al2s[s] + ald));
        unsigned u = h2b2[s * 8 + c];
        dsum += w;
        ax += w * bflo(u);
        ay += w * bfhi(u);
    }
    #pragma unroll
    for (int off = 8; off < 64; off <<= 1) {
        dsum += __shfl_xor(dsum, off, 64);
        ax   += __shfl_xor(ax, off, 64);
        ay   += __shfl_xor(ay, off, 64);
    }
    float inv = 1.f / dsum;
    float vx = ax * inv + b2[c * 2];
    float vy = ay * inv + b2[c * 2 + 1];

    // log_softmax over 16 channels = 8 lanes x 2
    float mx = fmaxf(vx, vy);
    #pragma unroll
    for (int off = 1; off < 8; off <<= 1) mx = fmaxf(mx, __shfl_xor(mx, off, 64));
    float se = __expf(vx - mx) + __expf(vy - mx);
    #pragma unroll
    for (int off = 1; off < 8; off <<= 1) se += __shfl_xor(se, off, 64);
    float ls = mx + __logf(se);
    if (j == 0)
        *(float2*)(out + (size_t)n * 16 + c * 2) = make_float2(vx - ls, vy - ls);
}

extern "C" void kernel_launch(void* const* d_in, const int* in_sizes, int n_in,
                              void* d_out, int out_size, void* d_ws, size_t ws_size,
                              hipStream_t stream)
{
    const float* x    = (const float*)d_in[0];
    const int*   eidx = (const int*)d_in[1];
    const float* W1   = (const float*)d_in[2];
    const float* a1s  = (const float*)d_in[3];
    const float* a1d  = (const float*)d_in[4];
    const float* b1   = (const float*)d_in[5];
    const float* W2   = (const float*)d_in[6];
    const float* a2s  = (const float*)d_in[7];
    const float* a2d  = (const float*)d_in[8];
    const float* b2   = (const float*)d_in[9];
    float* out = (float*)d_out;
    float* ws  = (float*)d_ws;

    const int* esrc = eidx;
    const int* edst = eidx + EE;

    int* gcnt = (int*)(ws + OFF_GCNT);
    int* base = (int*)(ws + OFF_BASE);
    int* row  = (int*)(ws + OFF_ROW);
    unsigned* bkt = (unsigned*)(ws + OFF_BKT);
    int* adj  = (int*)(ws + OFF_ADJ);
    unsigned short* h1b = (unsigned short*)(ws + OFF_H1B);
    uv4* h1bq = (uv4*)(ws + OFF_H1B);
    uv4* h1eq = (uv4*)(ws + OFF_H1E);
    float* al1s  = ws + OFF_AL1S;
    float* al1d  = ws + OFF_AL1D;
    unsigned short* h2b = (unsigned short*)(ws + OFF_H2B);
    float* al2s  = ws + OFF_AL2S;
    float* al2d  = ws + OFF_AL2D;

    hipMemsetAsync(gcnt, 0, 392 * sizeof(int), stream);

    k_binA <<<NABLK, 256, 0, stream>>>(esrc, edst, gcnt, bkt);
    k_scanB<<<1,     512, 0, stream>>>(gcnt, base, row);
    k_binC <<<NBKT,  256, 0, stream>>>(gcnt, base, bkt, row, adj);

    k_gemm1<<<(NN + 63) / 64, 256, 0, stream>>>(x, W1, a1s, a1d, h1b, al1s, al1d);
    k_agg1 <<<NN / 4, 256, 0, stream>>>(row, adj, al1s, al1d, h1bq, b1, h1eq);
    k_gemm2<<<NN / 16, 256, 0, stream>>>(h1eq, W2, a2s, a2d, h2b, al2s, al2d);
    k_agg2 <<<NN / 4, 256, 0, stream>>>(row, adj, al2s, al2d, (const unsigned*)h2b, b2, out);
}

// Round 10
// 419.036 us; speedup vs baseline: 1.0313x; 1.0313x over previous
//
#include <hip/hip_runtime.h>
#include <math.h>

#define NN   100000
#define EE   1600000
#define FIN  256
#define NCLS 16
#define NEG  0.2f

#define NEDGE (EE + NN)     // with self-loops
#define WBKT  256           // dsts per bucket
#define NBKT  ((NN + WBKT - 1) / WBKT)   // 391
#define CAP   5120          // per-bucket capacity (mean 4352)
#define ABLK  4096          // edges per binA block
#define NABLK ((NEDGE + ABLK - 1) / ABLK)  // 416

// ---- workspace layout (4-byte element offsets) ----
#define OFF_GCNT  0                          // [392] zeroed each call
#define OFF_BASE  392                        // [392]
#define OFF_ROW   784                        // [NN+1]
#define OFF_BKT   100788                     // [NBKT*CAP] packed (src<<8)|dlow
#define OFF_ADJ   (OFF_BKT + NBKT*CAP)       // [NEDGE]
#define OFF_H1B   (OFF_ADJ + NEDGE)          // [NN*64] bf16 (pre-attn values)
#define OFF_H1E   (OFF_H1B + NN*32)          // [NN*64] bf16 (post-ELU)
#define OFF_AL1S  (OFF_H1E + NN*32)          // [NN*8]
#define OFF_AL1D  (OFF_AL1S + NN*8)          // [NN*8]
#define OFF_H2B   (OFF_AL1D + NN*8)          // [NN*16] bf16
#define OFF_AL2S  (OFF_H2B + NN*8)           // [NN]
#define OFF_AL2D  (OFF_AL2S + NN)            // [NN]

typedef unsigned uv4 __attribute__((ext_vector_type(4)));
using bfrag = __attribute__((ext_vector_type(8))) short;   // 8 bf16 (4 VGPRs)
using ffrag = __attribute__((ext_vector_type(4))) float;   // MFMA C/D

__device__ __forceinline__ float lrelu(float x) { return x >= 0.f ? x : NEG * x; }
__device__ __forceinline__ unsigned short f2bf(float x) {
    unsigned u = __float_as_uint(x);
    return (unsigned short)((u + 0x7FFF + ((u >> 16) & 1)) >> 16);   // RNE
}
__device__ __forceinline__ float bf2f(unsigned short b) {
    return __uint_as_float(((unsigned)b) << 16);
}
__device__ __forceinline__ float bflo(unsigned u) { return __uint_as_float(u << 16); }
__device__ __forceinline__ float bfhi(unsigned u) { return __uint_as_float(u & 0xFFFF0000u); }

// ---------- CSR build, phase A: bin edges by dst>>8 ----------
__global__ __launch_bounds__(256) void k_binA(
    const int* __restrict__ esrc, const int* __restrict__ edst,
    int* __restrict__ gcnt, unsigned* __restrict__ bkt)
{
    __shared__ int lcnt[NBKT];
    __shared__ int lbase[NBKT];
    const int t = threadIdx.x;
    const int e0 = blockIdx.x * ABLK;
    for (int i = t; i < NBKT; i += 256) lcnt[i] = 0;
    __syncthreads();

    unsigned wrd[16];
    unsigned short bb[16], ll[16];
    #pragma unroll
    for (int j = 0; j < 16; ++j) {
        int ei = e0 + j * 256 + t;
        bb[j] = 0xFFFFu;
        if (ei < NEDGE) {
            int s, d;
            if (ei < EE) { s = esrc[ei]; d = edst[ei]; } else { s = d = ei - EE; }
            int b = d >> 8;
            wrd[j] = ((unsigned)s << 8) | (unsigned)(d & 255);
            bb[j] = (unsigned short)b;
            ll[j] = (unsigned short)atomicAdd(&lcnt[b], 1);
        }
    }
    __syncthreads();
    for (int i = t; i < NBKT; i += 256)
        lbase[i] = lcnt[i] ? atomicAdd(&gcnt[i], lcnt[i]) : 0;
    __syncthreads();
    #pragma unroll
    for (int j = 0; j < 16; ++j) {
        if (bb[j] != 0xFFFFu) {
            int b = bb[j];
            __builtin_nontemporal_store(wrd[j], &bkt[(size_t)b * CAP + lbase[b] + ll[j]]);
        }
    }
}

// ---------- CSR build, phase B: scan bucket counts -> bases ----------
__global__ __launch_bounds__(512) void k_scanB(
    const int* __restrict__ gcnt, int* __restrict__ base, int* __restrict__ row)
{
    __shared__ int s[512];
    int t = threadIdx.x;
    int v = (t < NBKT) ? gcnt[t] : 0;
    s[t] = v;
    __syncthreads();
    for (int off = 1; off < 512; off <<= 1) {
        int u = (t >= off) ? s[t - off] : 0;
        __syncthreads();
        s[t] += u;
        __syncthreads();
    }
    if (t <= NBKT) base[t] = s[t] - v;   // exclusive; base[NBKT] = NEDGE
    if (t == 0) row[NN] = NEDGE;
}

// ---------- CSR build, phase C: per-bucket local sort -> row + adj ----------
__global__ __launch_bounds__(256) void k_binC(
    const int* __restrict__ gcnt, const int* __restrict__ base,
    const unsigned* __restrict__ bkt, int* __restrict__ row, int* __restrict__ adj)
{
    __shared__ unsigned wd[CAP];          // 20 KB stage
    __shared__ int hist[256], pref[256], cnt2[256];
    const int g = blockIdx.x, t = threadIdx.x;
    const int cn = gcnt[g], bs = base[g];
    hist[t] = 0; cnt2[t] = 0;
    __syncthreads();
    for (int i = t; i < cn; i += 256) {
        unsigned w = __builtin_nontemporal_load(&bkt[(size_t)g * CAP + i]);
        wd[i] = w;
        atomicAdd(&hist[w & 255], 1);
    }
    __syncthreads();
    int v = hist[t];
    pref[t] = v;
    __syncthreads();
    for (int off = 1; off < 256; off <<= 1) {
        int u = (t >= off) ? pref[t - off] : 0;
        __syncthreads();
        pref[t] += u;
        __syncthreads();
    }
    int ex = pref[t] - v;                 // exclusive local prefix
    int n = g * 256 + t;
    if (n < NN) row[n] = bs + ex;
    pref[t] = ex;
    __syncthreads();
    for (int i = t; i < cn; i += 256) {
        unsigned w = wd[i];
        int dl = w & 255;
        int p = atomicAdd(&cnt2[dl], 1);
        adj[bs + pref[dl] + p] = (int)(w >> 8);
    }
}

// ---------- layer 1 GEMM via MFMA 16x16x32 bf16 ----------
// Block: 256 thr = 4 waves, 64 nodes x 64 cols. Wave w: rows w*16..+15, all 64 cols.
__global__ __launch_bounds__(256) void k_gemm1(
    const float* __restrict__ x, const float* __restrict__ W1,
    const float* __restrict__ a1s, const float* __restrict__ a1d,
    unsigned short* __restrict__ h1b, float* __restrict__ al1s, float* __restrict__ al1d)
{
    // B frags: sB[kc][quad][n][j] = bf16(W1[kc*32 + quad*8 + j][n]); 32 KB
    __shared__ short sB[8][4][64][8];
    const int t = threadIdx.x;
    for (int i = t; i < 256 * 64; i += 256) {
        int k = i >> 6, c = i & 63;
        sB[k >> 5][(k >> 3) & 3][c][k & 7] = (short)f2bf(W1[i]);
    }
    __syncthreads();

    const int w = t >> 6, lane = t & 63;
    const int m = lane & 15, q = lane >> 4;
    const int nrow = blockIdx.x * 64 + w * 16 + m;     // A-row this lane loads
    const bool rok = nrow < NN;
    const float* xr = x + (size_t)(rok ? nrow : 0) * FIN + q * 8;

    ffrag acc0 = {0.f, 0.f, 0.f, 0.f};
    ffrag acc1 = {0.f, 0.f, 0.f, 0.f};
    ffrag acc2 = {0.f, 0.f, 0.f, 0.f};
    ffrag acc3 = {0.f, 0.f, 0.f, 0.f};

    #pragma unroll
    for (int kc = 0; kc < 8; ++kc) {
        bfrag a = {0, 0, 0, 0, 0, 0, 0, 0};
        if (rok) {
            const float* p = xr + kc * 32;
            float4 p0 = *(const float4*)p;
            float4 p1 = *(const float4*)(p + 4);
            a[0] = (short)f2bf(p0.x); a[1] = (short)f2bf(p0.y);
            a[2] = (short)f2bf(p0.z); a[3] = (short)f2bf(p0.w);
            a[4] = (short)f2bf(p1.x); a[5] = (short)f2bf(p1.y);
            a[6] = (short)f2bf(p1.z); a[7] = (short)f2bf(p1.w);
        }
        bfrag b0 = *(const bfrag*)sB[kc][q][m];
        bfrag b1 = *(const bfrag*)sB[kc][q][16 + m];
        bfrag b2 = *(const bfrag*)sB[kc][q][32 + m];
        bfrag b3 = *(const bfrag*)sB[kc][q][48 + m];
        acc0 = __builtin_amdgcn_mfma_f32_16x16x32_bf16(a, b0, acc0, 0, 0, 0);
        acc1 = __builtin_amdgcn_mfma_f32_16x16x32_bf16(a, b1, acc1, 0, 0, 0);
        acc2 = __builtin_amdgcn_mfma_f32_16x16x32_bf16(a, b2, acc2, 0, 0, 0);
        acc3 = __builtin_amdgcn_mfma_f32_16x16x32_bf16(a, b3, acc3, 0, 0, 0);
    }

    // C/D: col = lane&15 (+16*nb), row = q*4 + r
    #pragma unroll
    for (int r = 0; r < 4; ++r) {
        int n = blockIdx.x * 64 + w * 16 + q * 4 + r;
        if (n < NN) {
            unsigned short* hp = h1b + (size_t)n * 64 + m;
            hp[0]  = f2bf(acc0[r]);
            hp[16] = f2bf(acc1[r]);
            hp[32] = f2bf(acc2[r]);
            hp[48] = f2bf(acc3[r]);
        }
    }

    // fused logits: per nb tile, 16 lanes hold 2 heads (8 cols each)
    const float sa0 = a1s[m], sa1 = a1s[16 + m], sa2 = a1s[32 + m], sa3 = a1s[48 + m];
    const float da0 = a1d[m], da1 = a1d[16 + m], da2 = a1d[32 + m], da3 = a1d[48 + m];
    #pragma unroll
    for (int r = 0; r < 4; ++r) {
        int n = blockIdx.x * 64 + w * 16 + q * 4 + r;
        float s0 = acc0[r] * sa0, s1 = acc1[r] * sa1, s2 = acc2[r] * sa2, s3 = acc3[r] * sa3;
        float d0 = acc0[r] * da0, d1 = acc1[r] * da1, d2 = acc2[r] * da2, d3 = acc3[r] * da3;
        #pragma unroll
        for (int off = 1; off < 8; off <<= 1) {
            s0 += __shfl_xor(s0, off, 64); d0 += __shfl_xor(d0, off, 64);
            s1 += __shfl_xor(s1, off, 64); d1 += __shfl_xor(d1, off, 64);
            s2 += __shfl_xor(s2, off, 64); d2 += __shfl_xor(d2, off, 64);
            s3 += __shfl_xor(s3, off, 64); d3 += __shfl_xor(d3, off, 64);
        }
        if ((m & 7) == 0 && n < NN) {
            int hb = m >> 3;   // 0 or 1
            al1s[n * 8 + 0 + hb] = s0;  al1d[n * 8 + 0 + hb] = d0;
            al1s[n * 8 + 2 + hb] = s1;  al1d[n * 8 + 2 + hb] = d1;
            al1s[n * 8 + 4 + hb] = s2;  al1d[n * 8 + 4 + hb] = d2;
            al1s[n * 8 + 6 + hb] = s3;  al1d[n * 8 + 6 + hb] = d3;
        }
    }
}

// ---------- layer 1 aggregation: 2 edges x 32 chpair-lanes, packed bf16x2 ----------
__global__ __launch_bounds__(256) void k_agg1(
    const int* __restrict__ row, const int* __restrict__ adj,
    const float* __restrict__ al1s, const float* __restrict__ al1d,
    const unsigned* __restrict__ h1b2, const float* __restrict__ b1,
    unsigned* __restrict__ h1e2)
{
    const int wv = threadIdx.x >> 6, lane = threadIdx.x & 63;
    const int n = blockIdx.x * 4 + wv;
    const int half = lane >> 5;        // which edge of the pair
    const int cp   = lane & 31;        // channel pair -> channels 2cp, 2cp+1
    const int h    = cp >> 2;          // head
    const float ald = al1d[n * 8 + h];
    const int r0 = row[n], r1 = row[n + 1];

    float dsum = 0.f, ax = 0.f, ay = 0.f;
    int i = r0;
    for (; i + 3 < r1; i += 4) {
        int i0 = i + half, i1 = i + 2 + half;
        int s0 = adj[i0], s1 = adj[i1];
        float w0 = __expf(lrelu(al1s[s0 * 8 + h] + ald));
        float w1 = __expf(lrelu(al1s[s1 * 8 + h] + ald));
        unsigned u0 = h1b2[s0 * 32 + cp];
        unsigned u1 = h1b2[s1 * 32 + cp];
        dsum += w0 + w1;
        ax += w0 * bflo(u0) + w1 * bflo(u1);
        ay += w0 * bfhi(u0) + w1 * bfhi(u1);
    }
    for (; i < r1; i += 2) {
        int i0 = i + half;
        bool act = i0 < r1;
        int s0 = adj[act ? i0 : r0];
        float w0 = act ? __expf(lrelu(al1s[s0 * 8 + h] + ald)) : 0.f;
        unsigned u0 = h1b2[s0 * 32 + cp];
        dsum += w0;
        ax += w0 * bflo(u0);
        ay += w0 * bfhi(u0);
    }
    dsum += __shfl_xor(dsum, 32, 64);
    ax   += __shfl_xor(ax, 32, 64);
    ay   += __shfl_xor(ay, 32, 64);

    float inv = 1.f / dsum;
    float vx = ax * inv + b1[cp * 2];
    float vy = ay * inv + b1[cp * 2 + 1];
    vx = vx > 0.f ? vx : __expf(vx) - 1.f;   // ELU fused
    vy = vy > 0.f ? vy : __expf(vy) - 1.f;
    if (half == 0)
        h1e2[n * 32 + cp] = (unsigned)f2bf(vx) | ((unsigned)f2bf(vy) << 16);
}

// ---------- layer 2 GEMM: h2b = bf16(h1e @ W2), al2s/al2d logits ----------
__global__ __launch_bounds__(256) void k_gemm2(
    const uv4* __restrict__ h1eq, const float* __restrict__ W2,
    const float* __restrict__ a2s, const float* __restrict__ a2d,
    unsigned short* __restrict__ h2b, float* __restrict__ al2s, float* __restrict__ al2d)
{
    __shared__ float sW[64 * 16];
    const int t = threadIdx.x;
    for (int i = t; i < 64 * 16; i += 256) sW[i] = W2[i];
    __syncthreads();
    const int n = blockIdx.x * 16 + (t >> 4);
    const int k = t & 15;
    const uv4* hr = h1eq + (size_t)n * 8;
    float acc = 0.f;
    #pragma unroll
    for (int q = 0; q < 8; ++q) {
        uv4 u = hr[q];
        acc += bflo(u.x) * sW[(q * 8 + 0) * 16 + k] + bfhi(u.x) * sW[(q * 8 + 1) * 16 + k]
             + bflo(u.y) * sW[(q * 8 + 2) * 16 + k] + bfhi(u.y) * sW[(q * 8 + 3) * 16 + k]
             + bflo(u.z) * sW[(q * 8 + 4) * 16 + k] + bfhi(u.z) * sW[(q * 8 + 5) * 16 + k]
             + bflo(u.w) * sW[(q * 8 + 6) * 16 + k] + bfhi(u.w) * sW[(q * 8 + 7) * 16 + k];
    }
    h2b[(size_t)n * 16 + k] = f2bf(acc);
    float vs = acc * a2s[k], vd = acc * a2d[k];
    #pragma unroll
    for (int off = 1; off < 16; off <<= 1) {
        vs += __shfl_xor(vs, off, 64);
        vd += __shfl_xor(vd, off, 64);
    }
    if (k == 0) { al2s[n] = vs; al2d[n] = vd; }
}

// ---------- layer 2 aggregation: 8 edges x 8 chpair-lanes, packed ----------
__global__ __launch_bounds__(256) void k_agg2(
    const int* __restrict__ row, const int* __restrict__ adj,
    const float* __restrict__ al2s, const float* __restrict__ al2d,
    const unsigned* __restrict__ h2b2, const float* __restrict__ b2,
    float* __restrict__ out)
{
    const int wv = threadIdx.x >> 6, lane = threadIdx.x & 63;
    const int n = blockIdx.x * 4 + wv;
    const float ald = al2d[n];
    const int r0 = row[n], r1 = row[n + 1];

    const int j = lane >> 3;    // edge slot 0..7
    const int c = lane & 7;     // channel pair -> channels 2c, 2c+1
    float dsum = 0.f, ax = 0.f, ay = 0.f;
    for (int i = r0; i < r1; i += 8) {
        int i0 = i + j;
        bool act = i0 < r1;
        int s = adj[act ? i0 : r0];
        float w = act ? __expf(lrelu(al2s[s] + ald)) : 0.f;
        unsigned u = h2b2[s * 8 + c];
        dsum += w;
        ax += w * bflo(u);
        ay += w * bfhi(u);
    }
    #pragma unroll
    for (int off = 8; off < 64; off <<= 1) {
        dsum += __shfl_xor(dsum, off, 64);
        ax   += __shfl_xor(ax, off, 64);
        ay   += __shfl_xor(ay, off, 64);
    }
    float inv = 1.f / dsum;
    float vx = ax * inv + b2[c * 2];
    float vy = ay * inv + b2[c * 2 + 1];

    // log_softmax over 16 channels = 8 lanes x 2
    float mx = fmaxf(vx, vy);
    #pragma unroll
    for (int off = 1; off < 8; off <<= 1) mx = fmaxf(mx, __shfl_xor(mx, off, 64));
    float se = __expf(vx - mx) + __expf(vy - mx);
    #pragma unroll
    for (int off = 1; off < 8; off <<= 1) se += __shfl_xor(se, off, 64);
    float ls = mx + __logf(se);
    if (j == 0)
        *(float2*)(out + (size_t)n * 16 + c * 2) = make_float2(vx - ls, vy - ls);
}

extern "C" void kernel_launch(void* const* d_in, const int* in_sizes, int n_in,
                              void* d_out, int out_size, void* d_ws, size_t ws_size,
                              hipStream_t stream)
{
    const float* x    = (const float*)d_in[0];
    const int*   eidx = (const int*)d_in[1];
    const float* W1   = (const float*)d_in[2];
    const float* a1s  = (const float*)d_in[3];
    const float* a1d  = (const float*)d_in[4];
    const float* b1   = (const float*)d_in[5];
    const float* W2   = (const float*)d_in[6];
    const float* a2s  = (const float*)d_in[7];
    const float* a2d  = (const float*)d_in[8];
    const float* b2   = (const float*)d_in[9];
    float* out = (float*)d_out;
    float* ws  = (float*)d_ws;

    const int* esrc = eidx;
    const int* edst = eidx + EE;

    int* gcnt = (int*)(ws + OFF_GCNT);
    int* base = (int*)(ws + OFF_BASE);
    int* row  = (int*)(ws + OFF_ROW);
    unsigned* bkt = (unsigned*)(ws + OFF_BKT);
    int* adj  = (int*)(ws + OFF_ADJ);
    unsigned short* h1b = (unsigned short*)(ws + OFF_H1B);
    uv4* h1eq = (uv4*)(ws + OFF_H1E);
    unsigned* h1e2 = (unsigned*)(ws + OFF_H1E);
    float* al1s  = ws + OFF_AL1S;
    float* al1d  = ws + OFF_AL1D;
    unsigned short* h2b = (unsigned short*)(ws + OFF_H2B);
    float* al2s  = ws + OFF_AL2S;
    float* al2d  = ws + OFF_AL2D;

    hipMemsetAsync(gcnt, 0, 392 * sizeof(int), stream);

    k_binA <<<NABLK, 256, 0, stream>>>(esrc, edst, gcnt, bkt);
    k_scanB<<<1,     512, 0, stream>>>(gcnt, base, row);
    k_binC <<<NBKT,  256, 0, stream>>>(gcnt, base, bkt, row, adj);

    k_gemm1<<<(NN + 63) / 64, 256, 0, stream>>>(x, W1, a1s, a1d, h1b, al1s, al1d);
    k_agg1 <<<NN / 4, 256, 0, stream>>>(row, adj, al1s, al1d, (const unsigned*)h1b, b1, h1e2);
    k_gemm2<<<NN / 16, 256, 0, stream>>>(h1eq, W2, a2s, a2d, h2b, al2s, al2d);
    k_agg2 <<<NN / 4, 256, 0, stream>>>(row, adj, al2s, al2d, (const unsigned*)h2b, b2, out);
}